// Round 1
// baseline (490.740 us; speedup 1.0000x reference)
//
#include <hip/hip_runtime.h>

#define N_NODES 100000
#define N_EDGES 1600000
#define IN_DIM 128
#define H1_DIM 64
#define H2_DIM 32
#define OUT_DIM 16

#define SCAN_BLK 256
#define NS1 ((N_NODES + SCAN_BLK - 1) / SCAN_BLK)   // 391

// ---------------- prep: Wc = W2@W1 [32x128], cvec = W2@b1 [32] ----------------
__global__ void prep_kernel(const float* __restrict__ W1, const float* __restrict__ b1,
                            const float* __restrict__ W2,
                            float* __restrict__ Wc, float* __restrict__ cvec) {
    int t = threadIdx.x;  // 256 threads, 1 block
    for (int idx = t; idx < H2_DIM * IN_DIM; idx += 256) {
        int j = idx >> 7, f = idx & 127;
        float acc = 0.f;
        for (int k = 0; k < H1_DIM; ++k)
            acc += W2[j * H1_DIM + k] * W1[k * IN_DIM + f];
        Wc[idx] = acc;
    }
    if (t < H2_DIM) {
        float acc = 0.f;
        for (int k = 0; k < H1_DIM; ++k)
            acc += W2[t * H1_DIM + k] * b1[k];
        cvec[t] = acc;
    }
}

// ---------------- degree count ----------------
__global__ void deg_kernel(const int* __restrict__ src, int* __restrict__ deg) {
    int e0 = blockIdx.x * blockDim.x + threadIdx.x;
    int stride = gridDim.x * blockDim.x;
    for (int e = e0; e < N_EDGES; e += stride) {
        unsigned s = (unsigned)src[e];
        if (s < N_NODES) atomicAdd(&deg[s], 1);
    }
}

// ---------------- 3-kernel exclusive scan of deg -> rs ----------------
__global__ void scan1_kernel(const int* __restrict__ deg, int* __restrict__ rs,
                             int* __restrict__ bsum) {
    __shared__ int s[SCAN_BLK];
    int t = threadIdx.x;
    int i = blockIdx.x * SCAN_BLK + t;
    int v = (i < N_NODES) ? deg[i] : 0;
    s[t] = v;
    __syncthreads();
    for (int off = 1; off < SCAN_BLK; off <<= 1) {
        int add = (t >= off) ? s[t - off] : 0;
        __syncthreads();
        s[t] += add;
        __syncthreads();
    }
    if (i < N_NODES) rs[i] = s[t] - v;      // exclusive within block
    if (t == SCAN_BLK - 1) bsum[blockIdx.x] = s[t];
}

__global__ void scan2_kernel(int* __restrict__ bsum, int* __restrict__ rs) {
    __shared__ int s[512];
    int t = threadIdx.x;  // 512 threads, 1 block
    int v = (t < NS1) ? bsum[t] : 0;
    s[t] = v;
    __syncthreads();
    for (int off = 1; off < 512; off <<= 1) {
        int add = (t >= off) ? s[t - off] : 0;
        __syncthreads();
        s[t] += add;
        __syncthreads();
    }
    if (t < NS1) bsum[t] = s[t] - v;        // exclusive block offsets
    if (t == 511) rs[N_NODES] = s[511];     // total = N_EDGES
}

__global__ void scan3_kernel(int* __restrict__ rs, const int* __restrict__ bsum,
                             int* __restrict__ cur) {
    int i = blockIdx.x * SCAN_BLK + threadIdx.x;
    if (i < N_NODES) {
        int r = rs[i] + bsum[i >> 8];
        rs[i] = r;
        cur[i] = r;
    }
}

// ---------------- scatter edges into CSR slots ----------------
__global__ void scatter_kernel(const int* __restrict__ src, const int* __restrict__ dst,
                               int* __restrict__ cur, int* __restrict__ sdst) {
    int e0 = blockIdx.x * blockDim.x + threadIdx.x;
    int stride = gridDim.x * blockDim.x;
    for (int e = e0; e < N_EDGES; e += stride) {
        unsigned s = (unsigned)src[e];
        if (s < N_NODES) {
            int p = atomicAdd(&cur[s], 1);
            sdst[p] = dst[e];
        }
    }
}

// ---------------- y = x @ Wc^T  [N,32] ----------------
__global__ __launch_bounds__(256) void gemmy_kernel(const float* __restrict__ x,
                                                    const float* __restrict__ Wc,
                                                    float* __restrict__ y) {
    __shared__ float wl[H2_DIM * 129];  // padded stride 129: conflict-free
    int t = threadIdx.x;
    for (int idx = t; idx < H2_DIM * IN_DIM; idx += 256) {
        int j = idx >> 7, f = idx & 127;
        wl[j * 129 + f] = Wc[idx];
    }
    __syncthreads();
    int g = t >> 5, j = t & 31;
    int i = blockIdx.x * 8 + g;
    if (i >= N_NODES) return;
    const float4* xr = (const float4*)(x + (size_t)i * IN_DIM);
    const float* wrow = wl + j * 129;
    float acc = 0.f;
#pragma unroll
    for (int k4 = 0; k4 < 32; ++k4) {
        float4 v = xr[k4];
        acc += v.x * wrow[4 * k4] + v.y * wrow[4 * k4 + 1] +
               v.z * wrow[4 * k4 + 2] + v.w * wrow[4 * k4 + 3];
    }
    y[(size_t)i * H2_DIM + j] = acc;
}

// ---------------- out[i,f] = sum_{e in CSR[i]} in[sdst[e], f] ----------------
__global__ __launch_bounds__(256) void agg_kernel(const float* __restrict__ in,
                                                  const int* __restrict__ rs,
                                                  const int* __restrict__ sdst,
                                                  float* __restrict__ out) {
    int t = threadIdx.x;
    int g = t >> 5, f = t & 31;
    int i = blockIdx.x * 8 + g;
    if (i >= N_NODES) return;
    int e0 = rs[i], e1 = rs[i + 1];
    float acc = 0.f;
    for (int e = e0; e < e1; ++e) {
        int d = sdst[e];  // broadcast across the 32 lanes
        acc += in[(size_t)d * H2_DIM + f];
    }
    out[(size_t)i * H2_DIM + f] = acc;
}

// ---------------- h2 = z2 + deg*c + b2 ; column-max into pk (uint keys) ------
__device__ inline unsigned f32_to_key(float v) {
    unsigned u = __float_as_uint(v);
    return (v >= 0.f) ? (u | 0x80000000u) : ~u;
}

__global__ __launch_bounds__(256) void finalize_kernel(const float* __restrict__ z2,
                                                       const int* __restrict__ deg,
                                                       const float* __restrict__ cvec,
                                                       const float* __restrict__ b2,
                                                       unsigned* __restrict__ pk) {
    __shared__ float sm[256];
    int t = threadIdx.x;
    int g = t >> 5, f = t & 31;
    float c = cvec[f];
    float bb = b2[f];
    float m = -3.402823466e+38f;
    int gid = blockIdx.x * 8 + g;
    int stride = gridDim.x * 8;
    for (int i = gid; i < N_NODES; i += stride) {
        float v = z2[(size_t)i * H2_DIM + f] + (float)deg[i] * c + bb;
        m = fmaxf(m, v);
    }
    sm[t] = m;
    __syncthreads();
    if (g == 0) {
        for (int k = 1; k < 8; ++k) m = fmaxf(m, sm[k * 32 + f]);
        atomicMax(&pk[f], f32_to_key(m));
    }
}

// ---------------- out = pooled @ Wf^T + bf ----------------
__global__ void final_kernel(const unsigned* __restrict__ pk,
                             const float* __restrict__ Wf,
                             const float* __restrict__ bfv,
                             float* __restrict__ out) {
    __shared__ float pooled[H2_DIM];
    int t = threadIdx.x;
    if (t < H2_DIM) {
        unsigned k = pk[t];
        unsigned u = (k & 0x80000000u) ? (k & 0x7FFFFFFFu) : ~k;
        pooled[t] = __uint_as_float(u);
    }
    __syncthreads();
    if (t < OUT_DIM) {
        float acc = bfv[t];
        for (int j = 0; j < H2_DIM; ++j)
            acc += Wf[t * H2_DIM + j] * pooled[j];
        out[t] = acc;
    }
}

extern "C" void kernel_launch(void* const* d_in, const int* in_sizes, int n_in,
                              void* d_out, int out_size, void* d_ws, size_t ws_size,
                              hipStream_t stream) {
    const float* x  = (const float*)d_in[0];
    const int*   ei = (const int*)d_in[1];           // [2, E]: row0 = src, row1 = dst
    const float* W1 = (const float*)d_in[2];
    const float* b1 = (const float*)d_in[3];
    const float* W2 = (const float*)d_in[4];
    const float* b2 = (const float*)d_in[5];
    const float* Wf = (const float*)d_in[6];
    const float* bf = (const float*)d_in[7];
    float* out = (float*)d_out;

    const int* src = ei;
    const int* dst = ei + N_EDGES;

    // workspace carve-up (all f32/i32, 4B)
    float* y    = (float*)d_ws;                      // N*32
    float* z1   = y  + (size_t)N_NODES * H2_DIM;     // N*32
    float* z2   = z1 + (size_t)N_NODES * H2_DIM;     // N*32
    float* Wc   = z2 + (size_t)N_NODES * H2_DIM;     // 32*128
    float* cvec = Wc + H2_DIM * IN_DIM;              // 32
    int*   deg  = (int*)(cvec + H2_DIM);             // N
    int*   rs   = deg + N_NODES;                     // N+1
    int*   cur  = rs + N_NODES + 1;                  // N
    int*   sdst = cur + N_NODES;                     // E
    int*   bsum = sdst + N_EDGES;                    // NS1
    unsigned* pk = (unsigned*)(bsum + NS1);          // 32

    hipMemsetAsync(deg, 0, (size_t)N_NODES * sizeof(int), stream);
    hipMemsetAsync(pk, 0, H2_DIM * sizeof(unsigned), stream);  // key 0 < all encodings

    prep_kernel<<<1, 256, 0, stream>>>(W1, b1, W2, Wc, cvec);
    deg_kernel<<<1024, 256, 0, stream>>>(src, deg);
    scan1_kernel<<<NS1, SCAN_BLK, 0, stream>>>(deg, rs, bsum);
    scan2_kernel<<<1, 512, 0, stream>>>(bsum, rs);
    scan3_kernel<<<NS1, SCAN_BLK, 0, stream>>>(rs, bsum, cur);
    scatter_kernel<<<1024, 256, 0, stream>>>(src, dst, cur, sdst);

    gemmy_kernel<<<(N_NODES + 7) / 8, 256, 0, stream>>>(x, Wc, y);

    agg_kernel<<<(N_NODES + 7) / 8, 256, 0, stream>>>(y,  rs, sdst, z1);
    agg_kernel<<<(N_NODES + 7) / 8, 256, 0, stream>>>(z1, rs, sdst, z2);

    finalize_kernel<<<1024, 256, 0, stream>>>(z2, deg, cvec, b2, pk);
    final_kernel<<<1, 64, 0, stream>>>(pk, Wf, bf, out);
}